// Round 6
// baseline (7989.334 us; speedup 1.0000x reference)
//
#include <hip/hip_runtime.h>
#include <hip/hip_bf16.h>
#include <hip/hip_fp16.h>

#define FDIM 128
#define NCH 8     // feature chunks of 16 floats (fp16 shadow chunk = 3.2 MB -> L2-resident)

// clang-native vector types for nontemporal builtins
typedef float vf2 __attribute__((ext_vector_type(2)));
typedef int   vi2 __attribute__((ext_vector_type(2)));

__device__ inline vf2 nt_load_f2(const float2* p) {
    return __builtin_nontemporal_load(reinterpret_cast<const vf2*>(p));
}
__device__ inline void nt_store_f2(float2* p, float x, float y) {
    vf2 v; v.x = x; v.y = y;
    __builtin_nontemporal_store(v, reinterpret_cast<vf2*>(p));
}
__device__ inline vi2 nt_load_i2(const int2* p) {
    return __builtin_nontemporal_load(reinterpret_cast<const vi2*>(p));
}

// ---------- degree / dinv ----------

__global__ void degree_kernel(const int* __restrict__ col, int* __restrict__ deg, int E) {
    int e = blockIdx.x * blockDim.x + threadIdx.x;
    if (e < E) atomicAdd(&deg[col[e]], 1);
}

__global__ void dinv_kernel(const int* __restrict__ deg, float* __restrict__ dinv, int N) {
    int i = blockIdx.x * blockDim.x + threadIdx.x;
    if (i < N) {
        int d = deg[i];
        dinv[i] = (d > 0) ? rsqrtf((float)d) : 0.0f;
    }
}

// ---------- exclusive scan of deg -> rowptr ----------

__global__ void scan_blocks_kernel(const int* __restrict__ deg, int* __restrict__ rowptr,
                                   int* __restrict__ bsum, int N) {
    __shared__ int s[256];
    int t = threadIdx.x;
    int i = blockIdx.x * 256 + t;
    int v = (i < N) ? deg[i] : 0;
    s[t] = v;
    __syncthreads();
    for (int off = 1; off < 256; off <<= 1) {
        int add = (t >= off) ? s[t - off] : 0;
        __syncthreads();
        s[t] += add;
        __syncthreads();
    }
    if (i < N) rowptr[i] = s[t] - v;
    if (t == 255) bsum[blockIdx.x] = s[255];
}

__global__ void scan_bsums_kernel(int* __restrict__ bsum, int* __restrict__ boff, int nb) {
    __shared__ int s[512];
    int t = threadIdx.x;
    int v = (t < nb) ? bsum[t] : 0;
    s[t] = v;
    __syncthreads();
    for (int off = 1; off < 512; off <<= 1) {
        int add = (t >= off) ? s[t - off] : 0;
        __syncthreads();
        s[t] += add;
        __syncthreads();
    }
    if (t < nb) boff[t] = s[t] - v;
}

__global__ void add_offsets_kernel(int* __restrict__ rowptr, int* __restrict__ cursor,
                                   const int* __restrict__ boff, int N, int E) {
    int i = blockIdx.x * blockDim.x + threadIdx.x;
    if (i < N) {
        int v = rowptr[i] + boff[i >> 8];
        rowptr[i] = v;
        cursor[i] = v;
    }
    if (i == 0) rowptr[N] = E;
}

// ---------- edge placement: CSR by destination, packed (idx, w) ----------

__global__ void place_kernel(const int* __restrict__ row, const int* __restrict__ col,
                             const float* __restrict__ dinv, int* __restrict__ cursor,
                             int2* __restrict__ edata, int E) {
    int e = blockIdx.x * blockDim.x + threadIdx.x;
    if (e < E) {
        int r = row[e], c = col[e];
        float w = dinv[r] * dinv[c];
        int pos = atomicAdd(&cursor[c], 1);
        edata[pos] = make_int2(r, __float_as_int(w));
    }
}

// ---------- convert: xh (fp16 chunk-major) ; outc init = mf[0]*x ----------

__global__ void convert_kernel(const float2* __restrict__ x2, const float* __restrict__ mf,
                               __half2* __restrict__ xh, float2* __restrict__ outc,
                               float2* __restrict__ out_nm, int N, long np) {
    long p = (long)blockIdx.x * blockDim.x + threadIdx.x;
    if (p >= np) return;
    long per_chunk = (long)N * 8;
    int c = (int)(p / per_chunk);
    long rem = p - (long)c * per_chunk;
    int node = (int)(rem >> 3);
    int j = (int)(rem & 7);
    long nm = ((long)node << 6) + (c << 3) + j;
    float2 v = x2[nm];
    xh[p] = __floats2half2_rn(v.x, v.y);
    float w = mf[0];
    float2 o = make_float2(w * v.x, w * v.y);
    if (outc) outc[p] = o;
    else      out_nm[nm] = o;
}

// ---------- chunked fused gather prop (group-per-node, 2 nodes/group) ----------
// block: chunk c = blockIdx&7 (XCD-affine). 256 thr = 4 waves; wave = 8 groups
// of 8 lanes; group g owns nodes nbase+g and nbase+8+g fully (no reduction).
// Lane j holds half2 features [2j,2j+1] of the 16-feature chunk.
// tgt = scale*gather + beta*prev2 (fp32); tgth = fp16(tgt); out += coef*tgt.
// Streams (edata/prev2/tgt/outc) are nontemporal to protect the L2-resident
// fp16 shadow chunk.

template <bool COUT>
__global__ __launch_bounds__(256) void prop_chunked_kernel(
        const int2* __restrict__ edata, const int* __restrict__ rowptr,
        const __half2* __restrict__ srch,
        const float2* __restrict__ prev2, int prev2_nm,
        float2* __restrict__ tgt, __half2* __restrict__ tgth,
        float2* __restrict__ outv,
        const float* __restrict__ mf, const float* __restrict__ lap,
        int i_coef, float scale, float beta, int N) {
    int c = blockIdx.x & 7;
    int blk = blockIdx.x >> 3;
    int wave = threadIdx.x >> 6;
    int lane = threadIdx.x & 63;
    int g = lane >> 3;
    int j = lane & 7;
    int nbase = blk * 64 + wave * 16;
    int n0 = nbase + g;
    int n1 = nbase + 8 + g;
    bool v0 = n0 < N, v1 = n1 < N;
    int b0 = 0, l0 = 0, b1 = 0, l1 = 0;
    if (v0) { int a = rowptr[n0]; b0 = a; l0 = rowptr[n0 + 1] - a; }
    if (v1) { int a = rowptr[n1]; b1 = a; l1 = rowptr[n1 + 1] - a; }
    long base = (long)c * N * 8;   // half2 units
    float ax0 = 0.f, ay0 = 0.f, ax1 = 0.f, ay1 = 0.f;
    int maxl = max(l0, l1);
    #pragma unroll 4
    for (int it = 0; it < maxl; ++it) {
        if (it < l0) {
            vi2 ed = nt_load_i2(&edata[b0 + it]);
            float w = __int_as_float(ed.y);
            float2 f = __half22float2(srch[base + ((long)ed.x << 3) + j]);
            ax0 += w * f.x; ay0 += w * f.y;
        }
        if (it < l1) {
            vi2 ed = nt_load_i2(&edata[b1 + it]);
            float w = __int_as_float(ed.y);
            float2 f = __half22float2(srch[base + ((long)ed.x << 3) + j]);
            ax1 += w * f.x; ay1 += w * f.y;
        }
    }
    float coef = mf[i_coef] * lap[i_coef - 1];
    // epilogue node n0
    if (v0) {
        long oc = ((long)c * N + n0) * 8 + j;
        float px = 0.f, py = 0.f;
        if (beta != 0.f) {
            vf2 p;
            if (prev2_nm) { float2 t = prev2[((long)n0 << 6) + (c << 3) + j]; p.x = t.x; p.y = t.y; }
            else          { p = nt_load_f2(&prev2[oc]); }
            px = p.x; py = p.y;
        }
        float tx = scale * ax0 + beta * px;
        float ty = scale * ay0 + beta * py;
        nt_store_f2(&tgt[oc], tx, ty);
        if (tgth) tgth[oc] = __floats2half2_rn(tx, ty);
        long oo = COUT ? oc : (((long)n0 << 6) + (c << 3) + j);
        vf2 ov = nt_load_f2(&outv[oo]);
        nt_store_f2(&outv[oo], ov.x + coef * tx, ov.y + coef * ty);
    }
    // epilogue node n1
    if (v1) {
        long oc = ((long)c * N + n1) * 8 + j;
        float px = 0.f, py = 0.f;
        if (beta != 0.f) {
            vf2 p;
            if (prev2_nm) { float2 t = prev2[((long)n1 << 6) + (c << 3) + j]; p.x = t.x; p.y = t.y; }
            else          { p = nt_load_f2(&prev2[oc]); }
            px = p.x; py = p.y;
        }
        float tx = scale * ax1 + beta * px;
        float ty = scale * ay1 + beta * py;
        nt_store_f2(&tgt[oc], tx, ty);
        if (tgth) tgth[oc] = __floats2half2_rn(tx, ty);
        long oo = COUT ? oc : (((long)n1 << 6) + (c << 3) + j);
        vf2 ov = nt_load_f2(&outv[oo]);
        nt_store_f2(&outv[oo], ov.x + coef * tx, ov.y + coef * ty);
    }
}

// ---------- final: chunk-major outc -> node-major out ----------

__global__ void transpose_out_kernel(const float2* __restrict__ outc,
                                     float2* __restrict__ out, int N, long np) {
    long p = (long)blockIdx.x * blockDim.x + threadIdx.x;
    if (p >= np) return;
    int node = (int)(p >> 6);
    int f2 = (int)(p & 63);
    int c = f2 >> 3, j = f2 & 7;
    out[p] = outc[((long)c * N + node) * 8 + j];
}

extern "C" void kernel_launch(void* const* d_in, const int* in_sizes, int n_in,
                              void* d_out, int out_size, void* d_ws, size_t ws_size,
                              hipStream_t stream) {
    const float* x   = (const float*)d_in[0];
    const float* mf  = (const float*)d_in[1];
    const float* lap = (const float*)d_in[2];
    const int*   ei  = (const int*)d_in[3];
    float* out = (float*)d_out;

    const int  K  = in_sizes[1] - 1;          // 10
    const long NF = (long)in_sizes[0];        // N*F
    const int  N  = (int)(NF / FDIM);         // 100000
    const int  E  = in_sizes[3] / 2;          // 3200000
    const int* row = ei;
    const int* col = ei + E;

    // workspace layout (256B-aligned bump allocator)
    size_t off = 0;
    auto alloc = [&](size_t bytes) -> void* {
        void* p = (char*)d_ws + off;
        off += (bytes + 255) & ~(size_t)255;
        return p;
    };
    float*  bufA   = (float*)alloc(NF * 4);
    float*  bufB   = (float*)alloc(NF * 4);
    __half* hA     = (__half*)alloc(NF * 2);
    __half* hB     = (__half*)alloc(NF * 2);   // also holds xh before i=2
    int2*   edata  = (int2*)alloc((size_t)E * 8);
    int*    rowptr = (int*)alloc((size_t)(N + 1) * 4);
    int*    cursor = (int*)alloc((size_t)N * 4);
    int*    deg    = (int*)alloc((size_t)N * 4);
    float*  dinv   = (float*)alloc((size_t)N * 4);
    int*    bsum   = (int*)alloc(512 * 4);
    int*    boff   = (int*)alloc(512 * 4);
    float* outc = nullptr;
    if (ws_size >= off + (size_t)NF * 4) outc = (float*)alloc(NF * 4);

    const int BT = 256;
    const int e_blocks = (E + BT - 1) / BT;
    const int n_blocks = (N + BT - 1) / BT;
    const long np = NF / 2;
    const int np_blocks = (int)((np + BT - 1) / BT);
    const int g_blocks = NCH * ((N + 63) / 64);   // 64 nodes per block

    // CSR build
    hipMemsetAsync(deg, 0, (size_t)N * sizeof(int), stream);
    degree_kernel<<<e_blocks, BT, 0, stream>>>(col, deg, E);
    dinv_kernel<<<n_blocks, BT, 0, stream>>>(deg, dinv, N);
    scan_blocks_kernel<<<n_blocks, BT, 0, stream>>>(deg, rowptr, bsum, N);
    scan_bsums_kernel<<<1, 512, 0, stream>>>(bsum, boff, n_blocks);
    add_offsets_kernel<<<n_blocks, BT, 0, stream>>>(rowptr, cursor, boff, N, E);
    place_kernel<<<e_blocks, BT, 0, stream>>>(row, col, dinv, cursor, edata, E);

    // xh = fp16 chunk-major x ; out init = mf0*x
    convert_kernel<<<np_blocks, BT, 0, stream>>>((const float2*)x, mf, (__half2*)hB,
                                                 (float2*)outc, (float2*)out, N, np);

    for (int i = 1; i <= K; ++i) {
        const __half* src   = (i == 1) ? hB : ((i % 2 == 0) ? hA : hB);
        float*        tgt   = (i % 2 == 0) ? bufB : bufA;
        __half*       tgth  = (i % 2 == 0) ? hB : hA;
        const float*  prev2 = (i <= 2) ? x : (const float*)tgt;
        int           pnm   = (i <= 2) ? 1 : 0;
        float         scale = (i == 1) ? 1.0f : 2.0f;
        float         beta  = (i == 1) ? 0.0f : -1.0f;
        if (i == K) tgth = nullptr;
        if (outc) {
            prop_chunked_kernel<true><<<g_blocks, BT, 0, stream>>>(
                edata, rowptr, (const __half2*)src, (const float2*)prev2, pnm,
                (float2*)tgt, (__half2*)tgth, (float2*)outc, mf, lap, i, scale, beta, N);
        } else {
            prop_chunked_kernel<false><<<g_blocks, BT, 0, stream>>>(
                edata, rowptr, (const __half2*)src, (const float2*)prev2, pnm,
                (float2*)tgt, (__half2*)tgth, (float2*)out, mf, lap, i, scale, beta, N);
        }
    }

    if (outc) {
        transpose_out_kernel<<<np_blocks, BT, 0, stream>>>((const float2*)outc,
                                                           (float2*)out, N, np);
    }
}

// Round 7
// 4564.265 us; speedup vs baseline: 1.7504x; 1.7504x over previous
//
#include <hip/hip_runtime.h>
#include <hip/hip_bf16.h>
#include <hip/hip_fp16.h>

#define FDIM 128
#define NCH 8     // feature chunks of 16 floats (fp16 shadow chunk = 3.2 MB/XCD)

// ---------- degree / dinv ----------

__global__ void degree_kernel(const int* __restrict__ col, int* __restrict__ deg, int E) {
    int e = blockIdx.x * blockDim.x + threadIdx.x;
    if (e < E) atomicAdd(&deg[col[e]], 1);
}

__global__ void dinv_kernel(const int* __restrict__ deg, float* __restrict__ dinv, int N) {
    int i = blockIdx.x * blockDim.x + threadIdx.x;
    if (i < N) {
        int d = deg[i];
        dinv[i] = (d > 0) ? rsqrtf((float)d) : 0.0f;
    }
}

// ---------- exclusive scan of deg -> rowptr ----------

__global__ void scan_blocks_kernel(const int* __restrict__ deg, int* __restrict__ rowptr,
                                   int* __restrict__ bsum, int N) {
    __shared__ int s[256];
    int t = threadIdx.x;
    int i = blockIdx.x * 256 + t;
    int v = (i < N) ? deg[i] : 0;
    s[t] = v;
    __syncthreads();
    for (int off = 1; off < 256; off <<= 1) {
        int add = (t >= off) ? s[t - off] : 0;
        __syncthreads();
        s[t] += add;
        __syncthreads();
    }
    if (i < N) rowptr[i] = s[t] - v;
    if (t == 255) bsum[blockIdx.x] = s[255];
}

__global__ void scan_bsums_kernel(int* __restrict__ bsum, int* __restrict__ boff, int nb) {
    __shared__ int s[512];
    int t = threadIdx.x;
    int v = (t < nb) ? bsum[t] : 0;
    s[t] = v;
    __syncthreads();
    for (int off = 1; off < 512; off <<= 1) {
        int add = (t >= off) ? s[t - off] : 0;
        __syncthreads();
        s[t] += add;
        __syncthreads();
    }
    if (t < nb) boff[t] = s[t] - v;
}

__global__ void add_offsets_kernel(int* __restrict__ rowptr, int* __restrict__ cursor,
                                   const int* __restrict__ boff, int N, int E) {
    int i = blockIdx.x * blockDim.x + threadIdx.x;
    if (i < N) {
        int v = rowptr[i] + boff[i >> 8];
        rowptr[i] = v;
        cursor[i] = v;
    }
    if (i == 0) rowptr[N] = E;
}

// ---------- edge placement: CSR by destination, packed (idx, w) ----------

__global__ void place_kernel(const int* __restrict__ row, const int* __restrict__ col,
                             const float* __restrict__ dinv, int* __restrict__ cursor,
                             int2* __restrict__ edata, int E) {
    int e = blockIdx.x * blockDim.x + threadIdx.x;
    if (e < E) {
        int r = row[e], c = col[e];
        float w = dinv[r] * dinv[c];
        int pos = atomicAdd(&cursor[c], 1);
        edata[pos] = make_int2(r, __float_as_int(w));
    }
}

// ---------- convert: xh (fp16 chunk-major) ; outc init = mf[0]*x ----------

__global__ void convert_kernel(const float2* __restrict__ x2, const float* __restrict__ mf,
                               __half2* __restrict__ xh, float2* __restrict__ outc,
                               float2* __restrict__ out_nm, int N, long np) {
    long p = (long)blockIdx.x * blockDim.x + threadIdx.x;
    if (p >= np) return;
    long per_chunk = (long)N * 8;
    int c = (int)(p / per_chunk);
    long rem = p - (long)c * per_chunk;
    int node = (int)(rem >> 3);
    int j = (int)(rem & 7);
    long nm = ((long)node << 6) + (c << 3) + j;
    float2 v = x2[nm];
    xh[p] = __floats2half2_rn(v.x, v.y);
    float w = mf[0];
    float2 o = make_float2(w * v.x, w * v.y);
    if (outc) outc[p] = o;
    else      out_nm[nm] = o;
}

// ---------- chunked fused gather prop (group-per-node, 2 nodes/group) ----------
// block: chunk c = blockIdx&7 (XCD-affine). 256 thr = 4 waves; wave = 8 groups
// of 8 lanes; group g owns nodes nbase+g and nbase+8+g fully (no reduction).
// Lane j holds half2 features [2j,2j+1] of the 16-feature chunk.
// tgt = scale*gather + beta*prev2 (fp32); tgth = fp16(tgt); out += coef*tgt.
// Plain cached accesses throughout: L3 absorbs the edata/stream re-reads
// (R6 lesson: nontemporal hints bypass L3 and octupled HBM fetch).

template <bool COUT>
__global__ __launch_bounds__(256) void prop_chunked_kernel(
        const int2* __restrict__ edata, const int* __restrict__ rowptr,
        const __half2* __restrict__ srch,
        const float2* __restrict__ prev2, int prev2_nm,
        float2* __restrict__ tgt, __half2* __restrict__ tgth,
        float2* __restrict__ outv,
        const float* __restrict__ mf, const float* __restrict__ lap,
        int i_coef, float scale, float beta, int N) {
    int c = blockIdx.x & 7;
    int blk = blockIdx.x >> 3;
    int wave = threadIdx.x >> 6;
    int lane = threadIdx.x & 63;
    int g = lane >> 3;
    int j = lane & 7;
    int nbase = blk * 64 + wave * 16;
    int n0 = nbase + g;
    int n1 = nbase + 8 + g;
    bool v0 = n0 < N, v1 = n1 < N;
    int b0 = 0, l0 = 0, b1 = 0, l1 = 0;
    if (v0) { int a = rowptr[n0]; b0 = a; l0 = rowptr[n0 + 1] - a; }
    if (v1) { int a = rowptr[n1]; b1 = a; l1 = rowptr[n1 + 1] - a; }
    long base = (long)c * N * 8;   // half2 units
    float ax0 = 0.f, ay0 = 0.f, ax1 = 0.f, ay1 = 0.f;
    int maxl = max(l0, l1);
    #pragma unroll 4
    for (int it = 0; it < maxl; ++it) {
        if (it < l0) {
            int2 ed = edata[b0 + it];
            float w = __int_as_float(ed.y);
            float2 f = __half22float2(srch[base + ((long)ed.x << 3) + j]);
            ax0 += w * f.x; ay0 += w * f.y;
        }
        if (it < l1) {
            int2 ed = edata[b1 + it];
            float w = __int_as_float(ed.y);
            float2 f = __half22float2(srch[base + ((long)ed.x << 3) + j]);
            ax1 += w * f.x; ay1 += w * f.y;
        }
    }
    float coef = mf[i_coef] * lap[i_coef - 1];
    // epilogue node n0
    if (v0) {
        long oc = ((long)c * N + n0) * 8 + j;
        float px = 0.f, py = 0.f;
        if (beta != 0.f) {
            float2 p = prev2_nm ? prev2[((long)n0 << 6) + (c << 3) + j] : prev2[oc];
            px = p.x; py = p.y;
        }
        float tx = scale * ax0 + beta * px;
        float ty = scale * ay0 + beta * py;
        tgt[oc] = make_float2(tx, ty);
        if (tgth) tgth[oc] = __floats2half2_rn(tx, ty);
        long oo = COUT ? oc : (((long)n0 << 6) + (c << 3) + j);
        float2 ov = outv[oo];
        ov.x += coef * tx; ov.y += coef * ty;
        outv[oo] = ov;
    }
    // epilogue node n1
    if (v1) {
        long oc = ((long)c * N + n1) * 8 + j;
        float px = 0.f, py = 0.f;
        if (beta != 0.f) {
            float2 p = prev2_nm ? prev2[((long)n1 << 6) + (c << 3) + j] : prev2[oc];
            px = p.x; py = p.y;
        }
        float tx = scale * ax1 + beta * px;
        float ty = scale * ay1 + beta * py;
        tgt[oc] = make_float2(tx, ty);
        if (tgth) tgth[oc] = __floats2half2_rn(tx, ty);
        long oo = COUT ? oc : (((long)n1 << 6) + (c << 3) + j);
        float2 ov = outv[oo];
        ov.x += coef * tx; ov.y += coef * ty;
        outv[oo] = ov;
    }
}

// ---------- final: chunk-major outc -> node-major out ----------

__global__ void transpose_out_kernel(const float2* __restrict__ outc,
                                     float2* __restrict__ out, int N, long np) {
    long p = (long)blockIdx.x * blockDim.x + threadIdx.x;
    if (p >= np) return;
    int node = (int)(p >> 6);
    int f2 = (int)(p & 63);
    int c = f2 >> 3, j = f2 & 7;
    out[p] = outc[((long)c * N + node) * 8 + j];
}

extern "C" void kernel_launch(void* const* d_in, const int* in_sizes, int n_in,
                              void* d_out, int out_size, void* d_ws, size_t ws_size,
                              hipStream_t stream) {
    const float* x   = (const float*)d_in[0];
    const float* mf  = (const float*)d_in[1];
    const float* lap = (const float*)d_in[2];
    const int*   ei  = (const int*)d_in[3];
    float* out = (float*)d_out;

    const int  K  = in_sizes[1] - 1;          // 10
    const long NF = (long)in_sizes[0];        // N*F
    const int  N  = (int)(NF / FDIM);         // 100000
    const int  E  = in_sizes[3] / 2;          // 3200000
    const int* row = ei;
    const int* col = ei + E;

    // workspace layout (256B-aligned bump allocator)
    size_t off = 0;
    auto alloc = [&](size_t bytes) -> void* {
        void* p = (char*)d_ws + off;
        off += (bytes + 255) & ~(size_t)255;
        return p;
    };
    float*  bufA   = (float*)alloc(NF * 4);
    float*  bufB   = (float*)alloc(NF * 4);
    __half* hA     = (__half*)alloc(NF * 2);
    __half* hB     = (__half*)alloc(NF * 2);   // also holds xh before i=2
    int2*   edata  = (int2*)alloc((size_t)E * 8);
    int*    rowptr = (int*)alloc((size_t)(N + 1) * 4);
    int*    cursor = (int*)alloc((size_t)N * 4);
    int*    deg    = (int*)alloc((size_t)N * 4);
    float*  dinv   = (float*)alloc((size_t)N * 4);
    int*    bsum   = (int*)alloc(512 * 4);
    int*    boff   = (int*)alloc(512 * 4);
    float* outc = nullptr;
    if (ws_size >= off + (size_t)NF * 4) outc = (float*)alloc(NF * 4);

    const int BT = 256;
    const int e_blocks = (E + BT - 1) / BT;
    const int n_blocks = (N + BT - 1) / BT;
    const long np = NF / 2;
    const int np_blocks = (int)((np + BT - 1) / BT);
    const int g_blocks = NCH * ((N + 63) / 64);   // 64 nodes per block

    // CSR build
    hipMemsetAsync(deg, 0, (size_t)N * sizeof(int), stream);
    degree_kernel<<<e_blocks, BT, 0, stream>>>(col, deg, E);
    dinv_kernel<<<n_blocks, BT, 0, stream>>>(deg, dinv, N);
    scan_blocks_kernel<<<n_blocks, BT, 0, stream>>>(deg, rowptr, bsum, N);
    scan_bsums_kernel<<<1, 512, 0, stream>>>(bsum, boff, n_blocks);
    add_offsets_kernel<<<n_blocks, BT, 0, stream>>>(rowptr, cursor, boff, N, E);
    place_kernel<<<e_blocks, BT, 0, stream>>>(row, col, dinv, cursor, edata, E);

    // xh = fp16 chunk-major x ; out init = mf0*x
    convert_kernel<<<np_blocks, BT, 0, stream>>>((const float2*)x, mf, (__half2*)hB,
                                                 (float2*)outc, (float2*)out, N, np);

    for (int i = 1; i <= K; ++i) {
        const __half* src   = (i == 1) ? hB : ((i % 2 == 0) ? hA : hB);
        float*        tgt   = (i % 2 == 0) ? bufB : bufA;
        __half*       tgth  = (i % 2 == 0) ? hB : hA;
        const float*  prev2 = (i <= 2) ? x : (const float*)tgt;
        int           pnm   = (i <= 2) ? 1 : 0;
        float         scale = (i == 1) ? 1.0f : 2.0f;
        float         beta  = (i == 1) ? 0.0f : -1.0f;
        if (i == K) tgth = nullptr;
        if (outc) {
            prop_chunked_kernel<true><<<g_blocks, BT, 0, stream>>>(
                edata, rowptr, (const __half2*)src, (const float2*)prev2, pnm,
                (float2*)tgt, (__half2*)tgth, (float2*)outc, mf, lap, i, scale, beta, N);
        } else {
            prop_chunked_kernel<false><<<g_blocks, BT, 0, stream>>>(
                edata, rowptr, (const __half2*)src, (const float2*)prev2, pnm,
                (float2*)tgt, (__half2*)tgth, (float2*)out, mf, lap, i, scale, beta, N);
        }
    }

    if (outc) {
        transpose_out_kernel<<<np_blocks, BT, 0, stream>>>((const float2*)outc,
                                                           (float2*)out, N, np);
    }
}